// Round 6
// baseline (700.268 us; speedup 1.0000x reference)
//
#include <hip/hip_runtime.h>

// GCN 2-layer forward, atomic-free aggregation via on-device CSR.
// x:[N,128] f32, edge_index:[2,E] int32, W1:[128,64], b1:[64], W2:[64,64], b2:[64]

#define FILL_CS 8192

// Count in-edges per dst, XCD-partitioned (same trick as k_fill): block b owns
// dst class b&7 = (d>>11)&7, so all atomic writers of a cnt line sit on one XCD.
__global__ __launch_bounds__(256) void k_count(const int* __restrict__ dst,
                                               int* __restrict__ cnt, int E) {
  int r = blockIdx.x & 7;
  int base = (blockIdx.x >> 3) * FILL_CS;
  int end = base + FILL_CS;
  if (end > E) end = E;
  for (int e = base + threadIdx.x; e < end; e += 256) {
    int d = dst[e];
    if (((d >> 11) & 7) == r) atomicAdd(&cnt[d], 1);
  }
}

__global__ __launch_bounds__(256) void k_dinv(const int* __restrict__ cnt,
                                              float* __restrict__ dinv, int N) {
  int i = blockIdx.x * 256 + threadIdx.x;
  if (i < N) dinv[i] = rsqrtf((float)cnt[i] + 1.0f);  // self-loop adds 1
}

// ---- 3-kernel exclusive scan of cnt[N] -> row[N], block sums in bsum ----
__global__ __launch_bounds__(256) void k_scan1(const int* __restrict__ cnt,
                                               int* __restrict__ row,
                                               int* __restrict__ bsum, int N) {
  __shared__ int tmp[256];
  int i = blockIdx.x * 256 + threadIdx.x;
  int v = (i < N) ? cnt[i] : 0;
  tmp[threadIdx.x] = v;
  __syncthreads();
  for (int off = 1; off < 256; off <<= 1) {
    int t = (threadIdx.x >= off) ? tmp[threadIdx.x - off] : 0;
    __syncthreads();
    tmp[threadIdx.x] += t;
    __syncthreads();
  }
  if (i < N) row[i] = tmp[threadIdx.x] - v;  // exclusive
  if (threadIdx.x == 255) bsum[blockIdx.x] = tmp[255];
}

__global__ __launch_bounds__(512) void k_scan2(int* __restrict__ bsum, int nb) {
  __shared__ int tmp[512];
  int v = (threadIdx.x < nb) ? bsum[threadIdx.x] : 0;
  tmp[threadIdx.x] = v;
  __syncthreads();
  for (int off = 1; off < 512; off <<= 1) {
    int t = (threadIdx.x >= off) ? tmp[threadIdx.x - off] : 0;
    __syncthreads();
    tmp[threadIdx.x] += t;
    __syncthreads();
  }
  if (threadIdx.x < nb) bsum[threadIdx.x] = tmp[threadIdx.x] - v;  // exclusive
}

__global__ __launch_bounds__(256) void k_scan3(int* __restrict__ row,
                                               const int* __restrict__ bsum,
                                               int N, int E) {
  int i = blockIdx.x * 256 + threadIdx.x;
  if (i < N) row[i] += bsum[blockIdx.x];
  if (i == 0) row[N] = E;
}

// Bin incoming edges by dst, XCD-partitioned (see k_count).
__global__ __launch_bounds__(256) void k_fill(const int* __restrict__ src,
                                              const int* __restrict__ dst,
                                              const int* __restrict__ row,
                                              int* __restrict__ fillc,
                                              int* __restrict__ eidx, int E) {
  int r = blockIdx.x & 7;
  int base = (blockIdx.x >> 3) * FILL_CS;
  int end = base + FILL_CS;
  if (end > E) end = E;
  for (int e = base + threadIdx.x; e < end; e += 256) {
    int d = dst[e];
    if (((d >> 11) & 7) == r) {
      int p = row[d] + atomicAdd(&fillc[d], 1);
      eidx[p] = src[e];
    }
  }
}

// HS[node, j] = dinv[node] * sum_k X[node, k] * W[k, j]   (W row-major [K,64])
// 4 threads per node, 16 output columns each: acc[16] stays in VGPRs
// (the acc[64] one-thread-per-node version spilled to scratch: VGPR=40,
// occupancy 16%, VALUBusy 11%). W loads hit 4 cache lines/wave (L1 broadcast).
template <int K>
__global__ __launch_bounds__(256) void k_gemm(const float* __restrict__ X,
                                              const float* __restrict__ W,
                                              const float* __restrict__ dinv,
                                              float* __restrict__ HS, int N) {
  int t = blockIdx.x * 256 + threadIdx.x;
  int node = t >> 2;
  if (node >= N) return;
  int j0 = (t & 3) * 16;
  const float* xr = X + (size_t)node * K;
  float acc[16];
#pragma unroll
  for (int j = 0; j < 16; ++j) acc[j] = 0.f;
  for (int k0 = 0; k0 < K; k0 += 4) {
    float4 xv = *reinterpret_cast<const float4*>(xr + k0);
#pragma unroll
    for (int i = 0; i < 4; ++i) {
      float xs = (i == 0) ? xv.x : (i == 1) ? xv.y : (i == 2) ? xv.z : xv.w;
      const float* wr = W + (size_t)(k0 + i) * 64 + j0;
#pragma unroll
      for (int jj = 0; jj < 16; jj += 4) {
        float4 wv = *reinterpret_cast<const float4*>(wr + jj);
        acc[jj + 0] = fmaf(xs, wv.x, acc[jj + 0]);
        acc[jj + 1] = fmaf(xs, wv.y, acc[jj + 1]);
        acc[jj + 2] = fmaf(xs, wv.z, acc[jj + 2]);
        acc[jj + 3] = fmaf(xs, wv.w, acc[jj + 3]);
      }
    }
  }
  float di = dinv[node];
  float* hr = HS + (size_t)node * 64 + j0;
#pragma unroll
  for (int j = 0; j < 16; j += 4) {
    float4 o;
    o.x = acc[j] * di; o.y = acc[j + 1] * di;
    o.z = acc[j + 2] * di; o.w = acc[j + 3] * di;
    *reinterpret_cast<float4*>(hr + j) = o;
  }
}

// One wave per node, lane = feature. hs rows are pre-scaled by dinv[src]:
// out[d] = dinv[d]*(sum_{s in in(d)} hs[s] + hs[d]) + bias   (+relu)
__global__ __launch_bounds__(256) void k_agg(const float* __restrict__ hs,
                                             const int* __restrict__ row,
                                             const int* __restrict__ eidx,
                                             const float* __restrict__ dinv,
                                             const float* __restrict__ bias,
                                             float* __restrict__ out, int N,
                                             int relu) {
  int gid = blockIdx.x * 256 + threadIdx.x;
  int node = gid >> 6, lane = gid & 63;
  if (node >= N) return;
  int beg = row[node], end = row[node + 1];
  float a0 = 0.f, a1 = 0.f, a2 = 0.f, a3 = 0.f;
  int e = beg;
  for (; e + 3 < end; e += 4) {
    int s0 = eidx[e], s1 = eidx[e + 1], s2 = eidx[e + 2], s3 = eidx[e + 3];
    a0 += hs[(size_t)s0 * 64 + lane];
    a1 += hs[(size_t)s1 * 64 + lane];
    a2 += hs[(size_t)s2 * 64 + lane];
    a3 += hs[(size_t)s3 * 64 + lane];
  }
  for (; e < end; ++e) a0 += hs[(size_t)eidx[e] * 64 + lane];
  float dd = dinv[node];
  float v = dd * ((a0 + a1) + (a2 + a3) + hs[(size_t)node * 64 + lane]) + bias[lane];
  if (relu) v = fmaxf(v, 0.f);
  out[(size_t)node * 64 + lane] = v;
}

extern "C" void kernel_launch(void* const* d_in, const int* in_sizes, int n_in,
                              void* d_out, int out_size, void* d_ws, size_t ws_size,
                              hipStream_t stream) {
  const float* x  = (const float*)d_in[0];
  const int*   ei = (const int*)d_in[1];
  const float* W1 = (const float*)d_in[2];
  const float* b1 = (const float*)d_in[3];
  const float* W2 = (const float*)d_in[4];
  const float* b2 = (const float*)d_in[5];
  float* out = (float*)d_out;

  const int N = in_sizes[0] / 128;  // 100000
  const int E = in_sizes[1] / 2;    // 1600000
  const int* src = ei;
  const int* dstv = ei + E;

  // workspace layout (4B units), ~33.6 MB total
  int*   cnt   = (int*)d_ws;                 // [N]
  int*   row   = cnt + 102400;               // [N+1]
  int*   fillc = cnt + 204800;               // [N]
  float* dinv  = (float*)(cnt + 307200);     // [N]
  int*   bsum  = cnt + 409600;               // [512]
  int*   eidx  = cnt + 410112;               // [E]
  float* bufA  = (float*)(cnt + 2010112);    // [N*64], 16B-aligned

  const int nb = (N + 255) / 256;
  const int nb4 = (N * 4 + 255) / 256;
  const int nchunk = (E + FILL_CS - 1) / FILL_CS;

  // ---- CSR build (shared by both convs) ----
  hipMemsetAsync(cnt, 0, (size_t)N * 4, stream);
  hipMemsetAsync(fillc, 0, (size_t)N * 4, stream);
  k_count<<<nchunk * 8, 256, 0, stream>>>(dstv, cnt, E);
  k_dinv<<<nb, 256, 0, stream>>>(cnt, dinv, N);
  k_scan1<<<nb, 256, 0, stream>>>(cnt, row, bsum, N);
  k_scan2<<<1, 512, 0, stream>>>(bsum, nb);
  k_scan3<<<nb, 256, 0, stream>>>(row, bsum, N, E);
  k_fill<<<nchunk * 8, 256, 0, stream>>>(src, dstv, row, fillc, eidx, E);

  // ---- conv1: hs1 = dinv*(x@W1) -> agg -> relu -> d_out ----
  k_gemm<128><<<nb4, 256, 0, stream>>>(x, W1, dinv, bufA, N);
  k_agg<<<(N * 64 + 255) / 256, 256, 0, stream>>>(bufA, row, eidx, dinv, b1, out, N, 1);

  // ---- conv2: hs2 = dinv*(out@W2) -> agg -> d_out ----
  k_gemm<64><<<nb4, 256, 0, stream>>>(out, W2, dinv, bufA, N);
  k_agg<<<(N * 64 + 255) / 256, 256, 0, stream>>>(bufA, row, eidx, dinv, b2, out, N, 0);
}

// Round 7
// 473.218 us; speedup vs baseline: 1.4798x; 1.4798x over previous
//
#include <hip/hip_runtime.h>

// GCN 2-layer forward, atomic-free aggregation via on-device CSR.
// x:[N,128] f32, edge_index:[2,E] int32, W1:[128,64], b1:[64], W2:[64,64], b2:[64]

#define FILL_CS 8192

// Count in-edges per dst, XCD-partitioned: block b owns dst class b&7 =
// (d>>11)&7, so all atomic writers of a cnt line sit on one XCD.
__global__ __launch_bounds__(256) void k_count(const int* __restrict__ dst,
                                               int* __restrict__ cnt, int E) {
  int r = blockIdx.x & 7;
  int base = (blockIdx.x >> 3) * FILL_CS;
  int end = base + FILL_CS;
  if (end > E) end = E;
  for (int e = base + threadIdx.x; e < end; e += 256) {
    int d = dst[e];
    if (((d >> 11) & 7) == r) atomicAdd(&cnt[d], 1);
  }
}

__global__ __launch_bounds__(256) void k_dinv(const int* __restrict__ cnt,
                                              float* __restrict__ dinv, int N) {
  int i = blockIdx.x * 256 + threadIdx.x;
  if (i < N) dinv[i] = rsqrtf((float)cnt[i] + 1.0f);  // self-loop adds 1
}

// ---- 3-kernel exclusive scan of cnt[N] -> row[N], block sums in bsum ----
__global__ __launch_bounds__(256) void k_scan1(const int* __restrict__ cnt,
                                               int* __restrict__ row,
                                               int* __restrict__ bsum, int N) {
  __shared__ int tmp[256];
  int i = blockIdx.x * 256 + threadIdx.x;
  int v = (i < N) ? cnt[i] : 0;
  tmp[threadIdx.x] = v;
  __syncthreads();
  for (int off = 1; off < 256; off <<= 1) {
    int t = (threadIdx.x >= off) ? tmp[threadIdx.x - off] : 0;
    __syncthreads();
    tmp[threadIdx.x] += t;
    __syncthreads();
  }
  if (i < N) row[i] = tmp[threadIdx.x] - v;  // exclusive
  if (threadIdx.x == 255) bsum[blockIdx.x] = tmp[255];
}

__global__ __launch_bounds__(512) void k_scan2(int* __restrict__ bsum, int nb) {
  __shared__ int tmp[512];
  int v = (threadIdx.x < nb) ? bsum[threadIdx.x] : 0;
  tmp[threadIdx.x] = v;
  __syncthreads();
  for (int off = 1; off < 512; off <<= 1) {
    int t = (threadIdx.x >= off) ? tmp[threadIdx.x - off] : 0;
    __syncthreads();
    tmp[threadIdx.x] += t;
    __syncthreads();
  }
  if (threadIdx.x < nb) bsum[threadIdx.x] = tmp[threadIdx.x] - v;  // exclusive
}

__global__ __launch_bounds__(256) void k_scan3(int* __restrict__ row,
                                               const int* __restrict__ bsum,
                                               int N, int E) {
  int i = blockIdx.x * 256 + threadIdx.x;
  if (i < N) row[i] += bsum[blockIdx.x];
  if (i == 0) row[N] = E;
}

// Bin incoming edges by dst, XCD-partitioned (see k_count).
__global__ __launch_bounds__(256) void k_fill(const int* __restrict__ src,
                                              const int* __restrict__ dst,
                                              const int* __restrict__ row,
                                              int* __restrict__ fillc,
                                              int* __restrict__ eidx, int E) {
  int r = blockIdx.x & 7;
  int base = (blockIdx.x >> 3) * FILL_CS;
  int end = base + FILL_CS;
  if (end > E) end = E;
  for (int e = base + threadIdx.x; e < end; e += 256) {
    int d = dst[e];
    if (((d >> 11) & 7) == r) {
      int p = row[d] + atomicAdd(&fillc[d], 1);
      eidx[p] = src[e];
    }
  }
}

// LDS-tiled GEMM: HS[node,j] = dinv[node] * sum_k X[node,k]*W[k,j].
// Block = 256 threads, tile = 64 nodes x 64 cols x full K in LDS.
// Each thread owns a 4x4 register tile (acc stays in VGPRs).
// History: acc[64]/thread -> scratch spill (VALUBusy 11%); per-lane VMEM W
// loads -> VMEM-issue bound (VALUBusy 5%). LDS staging fixes both.
// Xs padded [64][K+4]: 4-node column reads are 2-way bank-aliased (free).
template <int K>
__global__ __launch_bounds__(256) void k_gemm(const float* __restrict__ X,
                                              const float* __restrict__ W,
                                              const float* __restrict__ dinv,
                                              float* __restrict__ HS, int N) {
  __shared__ float Xs[64][K + 4];
  __shared__ float Ws[K][64];
  const int t = threadIdx.x;
  const int base = blockIdx.x * 64;

  // stage X tile (64 rows x K), coalesced float4 reads, b128 LDS writes
  for (int idx = t * 4; idx < 64 * K; idx += 1024) {
    int r = idx / K, c = idx % K;  // K is constexpr pow2 -> shifts
    float4 v = make_float4(0.f, 0.f, 0.f, 0.f);
    if (base + r < N)
      v = *reinterpret_cast<const float4*>(X + (size_t)(base + r) * K + c);
    *reinterpret_cast<float4*>(&Xs[r][c]) = v;  // (K+4)*4B row stride: 16B-aligned
  }
  // stage W (K x 64), flat copy
  for (int idx = t * 4; idx < K * 64; idx += 1024) {
    float4 v = *reinterpret_cast<const float4*>(W + idx);
    *reinterpret_cast<float4*>(&Ws[0][0] + idx) = v;
  }
  __syncthreads();

  const int n0 = (t >> 4) * 4;  // node sub-tile
  const int j0 = (t & 15) * 4;  // col sub-tile
  float acc[4][4];
#pragma unroll
  for (int i = 0; i < 4; ++i)
#pragma unroll
    for (int j = 0; j < 4; ++j) acc[i][j] = 0.f;

  for (int k0 = 0; k0 < K; k0 += 4) {
    float4 xv[4];
#pragma unroll
    for (int i = 0; i < 4; ++i)
      xv[i] = *reinterpret_cast<const float4*>(&Xs[n0 + i][k0]);
#pragma unroll
    for (int kk = 0; kk < 4; ++kk) {
      float4 wv = *reinterpret_cast<const float4*>(&Ws[k0 + kk][j0]);
#pragma unroll
      for (int i = 0; i < 4; ++i) {
        float xs = (kk == 0) ? xv[i].x : (kk == 1) ? xv[i].y
                 : (kk == 2) ? xv[i].z : xv[i].w;
        acc[i][0] = fmaf(xs, wv.x, acc[i][0]);
        acc[i][1] = fmaf(xs, wv.y, acc[i][1]);
        acc[i][2] = fmaf(xs, wv.z, acc[i][2]);
        acc[i][3] = fmaf(xs, wv.w, acc[i][3]);
      }
    }
  }

#pragma unroll
  for (int i = 0; i < 4; ++i) {
    int node = base + n0 + i;
    if (node < N) {
      float di = dinv[node];
      float4 o;
      o.x = acc[i][0] * di; o.y = acc[i][1] * di;
      o.z = acc[i][2] * di; o.w = acc[i][3] * di;
      *reinterpret_cast<float4*>(HS + (size_t)node * 64 + j0) = o;
    }
  }
}

// One wave per node, lane = feature. hs rows are pre-scaled by dinv[src]:
// out[d] = dinv[d]*(sum_{s in in(d)} hs[s] + hs[d]) + bias   (+relu)
__global__ __launch_bounds__(256) void k_agg(const float* __restrict__ hs,
                                             const int* __restrict__ row,
                                             const int* __restrict__ eidx,
                                             const float* __restrict__ dinv,
                                             const float* __restrict__ bias,
                                             float* __restrict__ out, int N,
                                             int relu) {
  int gid = blockIdx.x * 256 + threadIdx.x;
  int node = gid >> 6, lane = gid & 63;
  if (node >= N) return;
  int beg = row[node], end = row[node + 1];
  float a0 = 0.f, a1 = 0.f, a2 = 0.f, a3 = 0.f;
  int e = beg;
  for (; e + 3 < end; e += 4) {
    int s0 = eidx[e], s1 = eidx[e + 1], s2 = eidx[e + 2], s3 = eidx[e + 3];
    a0 += hs[(size_t)s0 * 64 + lane];
    a1 += hs[(size_t)s1 * 64 + lane];
    a2 += hs[(size_t)s2 * 64 + lane];
    a3 += hs[(size_t)s3 * 64 + lane];
  }
  for (; e < end; ++e) a0 += hs[(size_t)eidx[e] * 64 + lane];
  float dd = dinv[node];
  float v = dd * ((a0 + a1) + (a2 + a3) + hs[(size_t)node * 64 + lane]) + bias[lane];
  if (relu) v = fmaxf(v, 0.f);
  out[(size_t)node * 64 + lane] = v;
}

extern "C" void kernel_launch(void* const* d_in, const int* in_sizes, int n_in,
                              void* d_out, int out_size, void* d_ws, size_t ws_size,
                              hipStream_t stream) {
  const float* x  = (const float*)d_in[0];
  const int*   ei = (const int*)d_in[1];
  const float* W1 = (const float*)d_in[2];
  const float* b1 = (const float*)d_in[3];
  const float* W2 = (const float*)d_in[4];
  const float* b2 = (const float*)d_in[5];
  float* out = (float*)d_out;

  const int N = in_sizes[0] / 128;  // 100000
  const int E = in_sizes[1] / 2;    // 1600000
  const int* src = ei;
  const int* dstv = ei + E;

  // workspace layout (4B units), ~33.6 MB total
  int*   cnt   = (int*)d_ws;                 // [N]
  int*   row   = cnt + 102400;               // [N+1]
  int*   fillc = cnt + 204800;               // [N]
  float* dinv  = (float*)(cnt + 307200);     // [N]
  int*   bsum  = cnt + 409600;               // [512]
  int*   eidx  = cnt + 410112;               // [E]
  float* bufA  = (float*)(cnt + 2010112);    // [N*64], 16B-aligned

  const int nb = (N + 255) / 256;
  const int ngemm = (N + 63) / 64;
  const int nchunk = (E + FILL_CS - 1) / FILL_CS;

  // ---- CSR build (shared by both convs) ----
  hipMemsetAsync(cnt, 0, (size_t)N * 4, stream);
  hipMemsetAsync(fillc, 0, (size_t)N * 4, stream);
  k_count<<<nchunk * 8, 256, 0, stream>>>(dstv, cnt, E);
  k_dinv<<<nb, 256, 0, stream>>>(cnt, dinv, N);
  k_scan1<<<nb, 256, 0, stream>>>(cnt, row, bsum, N);
  k_scan2<<<1, 512, 0, stream>>>(bsum, nb);
  k_scan3<<<nb, 256, 0, stream>>>(row, bsum, N, E);
  k_fill<<<nchunk * 8, 256, 0, stream>>>(src, dstv, row, fillc, eidx, E);

  // ---- conv1: hs1 = dinv*(x@W1) -> agg -> relu -> d_out ----
  k_gemm<128><<<ngemm, 256, 0, stream>>>(x, W1, dinv, bufA, N);
  k_agg<<<(N * 64 + 255) / 256, 256, 0, stream>>>(bufA, row, eidx, dinv, b1, out, N, 1);

  // ---- conv2: hs2 = dinv*(out@W2) -> agg -> d_out ----
  k_gemm<64><<<ngemm, 256, 0, stream>>>(out, W2, dinv, bufA, N);
  k_agg<<<(N * 64 + 255) / 256, 256, 0, stream>>>(bufA, row, eidx, dinv, b2, out, N, 0);
}